// Round 3
// baseline (1573.304 us; speedup 1.0000x reference)
//
#include <hip/hip_runtime.h>

#define NDIM 64
#define EDIM 16
#define SCAN_BS 256
#define SCAN_TILE 2048   // SCAN_BS * 8

// ---------------- CSR build ----------------

__global__ __launch_bounds__(256) void hist_kernel(const int* __restrict__ edge_index,
                                                   int* __restrict__ deg, int E) {
    int e = blockIdx.x * blockDim.x + threadIdx.x;
    if (e < E) atomicAdd(&deg[edge_index[E + e]], 1);   // dst row
}

__global__ __launch_bounds__(SCAN_BS) void scan_tile_kernel(const int* __restrict__ deg,
                                                            int* __restrict__ excl,
                                                            int* __restrict__ tsum, int n) {
    __shared__ int sdata[SCAN_BS];
    int base = blockIdx.x * SCAN_TILE + threadIdx.x * 8;
    int v[8]; int s = 0;
#pragma unroll
    for (int j = 0; j < 8; ++j) { int idx = base + j; int val = (idx < n) ? deg[idx] : 0; v[j] = val; s += val; }
    sdata[threadIdx.x] = s;
    __syncthreads();
    for (int off = 1; off < SCAN_BS; off <<= 1) {
        int t = (threadIdx.x >= (unsigned)off) ? sdata[threadIdx.x - off] : 0;
        __syncthreads();
        sdata[threadIdx.x] += t;
        __syncthreads();
    }
    int incl = sdata[threadIdx.x];
    if (threadIdx.x == SCAN_BS - 1) tsum[blockIdx.x] = incl;
    int run = incl - s;  // exclusive prefix for this thread's chunk
#pragma unroll
    for (int j = 0; j < 8; ++j) { int idx = base + j; if (idx < n) excl[idx] = run; run += v[j]; }
}

__global__ void scan_sums_kernel(int* tsum, int ntiles) {
    if (threadIdx.x == 0 && blockIdx.x == 0) {
        int run = 0;
        for (int i = 0; i < ntiles; ++i) { int t = tsum[i]; tsum[i] = run; run += t; }
    }
}

__global__ __launch_bounds__(256) void scan_add_kernel(int* __restrict__ rowptr,
                                                       const int* __restrict__ tsum,
                                                       int* __restrict__ fillc, int n, int E) {
    int i = blockIdx.x * blockDim.x + threadIdx.x;
    if (i < n) {
        int v = rowptr[i] + tsum[i / SCAN_TILE];
        rowptr[i] = v;
        fillc[i] = v;
    }
    if (i == 0) rowptr[n] = E;
}

// fill + permute edge_attr into CSR order
__global__ __launch_bounds__(256) void fill2_kernel(const int* __restrict__ edge_index,
                                                    int* __restrict__ fillc,
                                                    int* __restrict__ srcs,
                                                    float4* __restrict__ gea,
                                                    const float4* __restrict__ ea, int E) {
    int e = blockIdx.x * blockDim.x + threadIdx.x;
    if (e < E) {
        int d = edge_index[E + e];
        int pos = atomicAdd(&fillc[d], 1);
        srcs[pos] = edge_index[e];
        float4 r0 = ea[(size_t)e*4+0], r1 = ea[(size_t)e*4+1],
               r2 = ea[(size_t)e*4+2], r3 = ea[(size_t)e*4+3];
        gea[(size_t)pos*4+0] = r0; gea[(size_t)pos*4+1] = r1;
        gea[(size_t)pos*4+2] = r2; gea[(size_t)pos*4+3] = r3;
    }
}

// fallback fill (no permuted ea) for small ws
__global__ __launch_bounds__(256) void fill_kernel(const int* __restrict__ edge_index,
                                                   int* __restrict__ fillc,
                                                   int* __restrict__ srcs,
                                                   int* __restrict__ eids, int E) {
    int e = blockIdx.x * blockDim.x + threadIdx.x;
    if (e < E) {
        int d = edge_index[E + e];
        int pos = atomicAdd(&fillc[d], 1);
        srcs[pos] = edge_index[e];
        eids[pos] = e;
    }
}

#define EDGE_FMA16(m, A0, A1, A2, A3)                                   \
    m = fmaf(A0.x, le[ 0], m); m = fmaf(A0.y, le[ 1], m);               \
    m = fmaf(A0.z, le[ 2], m); m = fmaf(A0.w, le[ 3], m);               \
    m = fmaf(A1.x, le[ 4], m); m = fmaf(A1.y, le[ 5], m);               \
    m = fmaf(A1.z, le[ 6], m); m = fmaf(A1.w, le[ 7], m);               \
    m = fmaf(A2.x, le[ 8], m); m = fmaf(A2.y, le[ 9], m);               \
    m = fmaf(A2.z, le[10], m); m = fmaf(A2.w, le[11], m);               \
    m = fmaf(A3.x, le[12], m); m = fmaf(A3.y, le[13], m);               \
    m = fmaf(A3.z, le[14], m); m = fmaf(A3.w, le[15], m);

// ---------------- aggregation kernel (latency phase) ----------------
// Zero LDS -> occupancy bound only by VGPRs. One wave per node, lane = channel.
// h = (1+eps)*x + sum_j relu(x[src_j] + ea_j @ lin_e), written to hout.

__global__ __launch_bounds__(256) void aggr_kernel(
    const float* __restrict__ xin, float* __restrict__ hout,
    const int* __restrict__ rowptr, const int* __restrict__ srcs,
    const float* __restrict__ gea,
    const float* __restrict__ lin_e, const float* __restrict__ eps,
    int layer, int n_nodes)
{
    const int lane = threadIdx.x & 63;
    float le[16];
    const float* lep = lin_e + (size_t)layer * EDIM * NDIM;
#pragma unroll
    for (int j = 0; j < EDIM; ++j) le[j] = lep[j * NDIM + lane];
    const float eps1 = 1.0f + eps[layer];

    int gw = (blockIdx.x * blockDim.x + threadIdx.x) >> 6;
    int nw = (gridDim.x * blockDim.x) >> 6;
    for (int node = gw; node < n_nodes; node += nw) {
        int p0 = rowptr[node], p1 = rowptr[node + 1];
        float aggr = 0.0f;
        for (int base = p0; base < p1; base += 64) {
            int cnt = min(64, p1 - base);
            int s_l = (lane < cnt) ? srcs[base + lane] : 0;
            int p = 0;
            for (; p + 4 <= cnt; p += 4) {
                int s0 = __shfl(s_l, p), s1 = __shfl(s_l, p + 1),
                    s2 = __shfl(s_l, p + 2), s3 = __shfl(s_l, p + 3);
                float xs0 = xin[(size_t)s0 * NDIM + lane];
                float xs1 = xin[(size_t)s1 * NDIM + lane];
                float xs2 = xin[(size_t)s2 * NDIM + lane];
                float xs3 = xin[(size_t)s3 * NDIM + lane];
                const float4* ea = (const float4*)(gea + (size_t)(base + p) * EDIM);
                float4 a0 = ea[ 0], a1 = ea[ 1], a2 = ea[ 2], a3 = ea[ 3];
                float4 e0 = ea[ 4], e1 = ea[ 5], e2 = ea[ 6], e3 = ea[ 7];
                float4 c0 = ea[ 8], c1 = ea[ 9], c2 = ea[10], c3 = ea[11];
                float4 d0 = ea[12], d1 = ea[13], d2 = ea[14], d3 = ea[15];
                float m0 = xs0, m1 = xs1, m2 = xs2, m3 = xs3;
                EDGE_FMA16(m0, a0, a1, a2, a3)
                EDGE_FMA16(m1, e0, e1, e2, e3)
                EDGE_FMA16(m2, c0, c1, c2, c3)
                EDGE_FMA16(m3, d0, d1, d2, d3)
                aggr += fmaxf(m0, 0.0f) + fmaxf(m1, 0.0f) + fmaxf(m2, 0.0f) + fmaxf(m3, 0.0f);
            }
            for (; p < cnt; ++p) {
                int s0 = __shfl(s_l, p);
                float xs0 = xin[(size_t)s0 * NDIM + lane];
                const float4* ea = (const float4*)(gea + (size_t)(base + p) * EDIM);
                float4 a0 = ea[0], a1 = ea[1], a2 = ea[2], a3 = ea[3];
                float m0 = xs0;
                EDGE_FMA16(m0, a0, a1, a2, a3)
                aggr += fmaxf(m0, 0.0f);
            }
        }
        hout[(size_t)node * NDIM + lane] = fmaf(eps1, xin[(size_t)node * NDIM + lane], aggr);
    }
}

// ---------------- MLP kernel (compute phase, in-place) ----------------
// 2 nodes per wave interleaved: one ds_read of the weight serves two FMAs.
// In-place safe: each wave reads its own rows fully before writing them.

__global__ __launch_bounds__(256) void mlp_kernel(
    float* __restrict__ h,
    const float* __restrict__ W1, const float* __restrict__ b1,
    const float* __restrict__ W2, const float* __restrict__ b2,
    int layer, int n_nodes)
{
    __shared__ float s_W1[NDIM * NDIM];
    __shared__ float s_W2[NDIM * NDIM];
    const float* w1 = W1 + (size_t)layer * NDIM * NDIM;
    const float* w2 = W2 + (size_t)layer * NDIM * NDIM;
    for (int i = threadIdx.x; i < NDIM * NDIM; i += 256) { s_W1[i] = w1[i]; s_W2[i] = w2[i]; }
    const int lane = threadIdx.x & 63;
    const float bb1 = b1[layer * NDIM + lane];
    const float bb2 = b2[layer * NDIM + lane];
    __syncthreads();

    int gw = (blockIdx.x * blockDim.x + threadIdx.x) >> 6;
    int nw = (gridDim.x * blockDim.x) >> 6;
    for (int n0 = gw * 2; n0 < n_nodes; n0 += nw * 2) {
        int n1 = n0 + 1;
        bool has1 = (n1 < n_nodes);
        float h0 = h[(size_t)n0 * NDIM + lane];
        float h1 = has1 ? h[(size_t)n1 * NDIM + lane] : 0.0f;
        float oa = bb1, ob = bb1;
#pragma unroll
        for (int k = 0; k < NDIM; ++k) {
            float w = s_W1[k * NDIM + lane];
            oa = fmaf(__shfl(h0, k), w, oa);
            ob = fmaf(__shfl(h1, k), w, ob);
        }
        oa = fmaxf(oa, 0.0f); ob = fmaxf(ob, 0.0f);
        float pa = bb2, pb = bb2;
#pragma unroll
        for (int k = 0; k < NDIM; ++k) {
            float w = s_W2[k * NDIM + lane];
            pa = fmaf(__shfl(oa, k), w, pa);
            pb = fmaf(__shfl(ob, k), w, pb);
        }
        h[(size_t)n0 * NDIM + lane] = fmaxf(pa, 0.0f);
        if (has1) h[(size_t)n1 * NDIM + lane] = fmaxf(pb, 0.0f);
    }
}

// fallback fused layer (round-2 version, eids-based) for small ws
__global__ __launch_bounds__(256) void layer_kernel(
    const float* __restrict__ xin, float* __restrict__ xout,
    const int* __restrict__ rowptr, const int* __restrict__ srcs, const int* __restrict__ eids,
    const float* __restrict__ edge_attr,
    const float* __restrict__ lin_e, const float* __restrict__ W1, const float* __restrict__ b1,
    const float* __restrict__ W2, const float* __restrict__ b2, const float* __restrict__ eps,
    int layer, int n_nodes)
{
    __shared__ float s_W1[NDIM * NDIM];
    __shared__ float s_W2[NDIM * NDIM];
    const float* w1 = W1 + (size_t)layer * NDIM * NDIM;
    const float* w2 = W2 + (size_t)layer * NDIM * NDIM;
    for (int i = threadIdx.x; i < NDIM * NDIM; i += 256) { s_W1[i] = w1[i]; s_W2[i] = w2[i]; }
    const int lane = threadIdx.x & 63;
    float le[16];
    const float* lep = lin_e + (size_t)layer * EDIM * NDIM;
#pragma unroll
    for (int j = 0; j < EDIM; ++j) le[j] = lep[j * NDIM + lane];
    const float bb1 = b1[layer * NDIM + lane];
    const float bb2 = b2[layer * NDIM + lane];
    const float eps1 = 1.0f + eps[layer];
    __syncthreads();
    int gw = (blockIdx.x * blockDim.x + threadIdx.x) >> 6;
    int nw = (gridDim.x * blockDim.x) >> 6;
    for (int node = gw; node < n_nodes; node += nw) {
        int p0 = rowptr[node], p1 = rowptr[node + 1];
        float aggr = 0.0f;
        for (int p = p0; p < p1; ++p) {
            int s = srcs[p];
            int e = eids[p];
            float xs = xin[(size_t)s * NDIM + lane];
            const float4* ea = (const float4*)(edge_attr + (size_t)e * EDIM);
            float4 a0 = ea[0], a1 = ea[1], a2 = ea[2], a3 = ea[3];
            float m0 = xs;
            EDGE_FMA16(m0, a0, a1, a2, a3)
            aggr += fmaxf(m0, 0.0f);
        }
        float h = fmaf(eps1, xin[(size_t)node * NDIM + lane], aggr);
        float o1 = bb1;
#pragma unroll 8
        for (int k = 0; k < NDIM; ++k) o1 = fmaf(__shfl(h, k), s_W1[k * NDIM + lane], o1);
        o1 = fmaxf(o1, 0.0f);
        float o2 = bb2;
#pragma unroll 8
        for (int k = 0; k < NDIM; ++k) o2 = fmaf(__shfl(o1, k), s_W2[k * NDIM + lane], o2);
        xout[(size_t)node * NDIM + lane] = fmaxf(o2, 0.0f);
    }
}

// ---------------- pooling + head (atomic-free: batch is sorted) ----------------

__global__ __launch_bounds__(256) void starts_kernel(const int* __restrict__ batch,
                                                     int* __restrict__ starts, int N, int G) {
    int g = blockIdx.x * blockDim.x + threadIdx.x;
    if (g <= G) {
        int lo = 0, hi = N;
        while (lo < hi) { int mid = (lo + hi) >> 1; if (batch[mid] < g) lo = mid + 1; else hi = mid; }
        starts[g] = lo;
    }
}

__global__ __launch_bounds__(256) void poolhead_kernel(const float* __restrict__ x,
                                                       const int* __restrict__ starts,
                                                       const float* __restrict__ t_cond,
                                                       const float* __restrict__ hW1,
                                                       const float* __restrict__ hb1,
                                                       const float* __restrict__ hW2,
                                                       const float* __restrict__ hb2,
                                                       float* __restrict__ out, int G) {
    __shared__ float sW1[(NDIM + 1) * NDIM];
    __shared__ float sb1[NDIM];
    __shared__ float sW2[NDIM];
    for (int i = threadIdx.x; i < (NDIM + 1) * NDIM; i += 256) sW1[i] = hW1[i];
    if (threadIdx.x < NDIM) { sb1[threadIdx.x] = hb1[threadIdx.x]; sW2[threadIdx.x] = hW2[threadIdx.x]; }
    __syncthreads();
    const int lane = threadIdx.x & 63;
    int gw = (blockIdx.x * blockDim.x + threadIdx.x) >> 6;
    int nw = (gridDim.x * blockDim.x) >> 6;
    for (int g = gw; g < G; g += nw) {
        int a = starts[g], b = starts[g + 1];
        float s0 = 0.0f, s1 = 0.0f;
        int n = a;
        for (; n + 2 <= b; n += 2) {
            s0 += x[(size_t)n * NDIM + lane];
            s1 += x[(size_t)(n + 1) * NDIM + lane];
        }
        if (n < b) s0 += x[(size_t)n * NDIM + lane];
        float c = fmaxf((float)(b - a), 1.0f);
        float p = (s0 + s1) / c;
        float t = t_cond[g];
        float o1 = fmaf(t, sW1[NDIM * NDIM + lane], sb1[lane]);
#pragma unroll 8
        for (int k = 0; k < NDIM; ++k) o1 = fmaf(__shfl(p, k), sW1[k * NDIM + lane], o1);
        o1 = fmaxf(o1, 0.0f);
        float v = o1 * sW2[lane];
        for (int off = 32; off > 0; off >>= 1) v += __shfl_down(v, off);
        if (lane == 0) out[g] = v + hb2[0];
    }
}

// ---------------- launch ----------------

extern "C" void kernel_launch(void* const* d_in, const int* in_sizes, int n_in,
                              void* d_out, int out_size, void* d_ws, size_t ws_size,
                              hipStream_t stream) {
    const float* x_in      = (const float*)d_in[0];
    const int*   edge_index= (const int*)  d_in[1];
    const float* edge_attr = (const float*)d_in[2];
    const int*   batch     = (const int*)  d_in[3];
    const float* t_cond    = (const float*)d_in[4];
    const float* lin_e     = (const float*)d_in[5];
    const float* W1        = (const float*)d_in[6];
    const float* b1        = (const float*)d_in[7];
    const float* W2        = (const float*)d_in[8];
    const float* b2        = (const float*)d_in[9];
    const float* eps       = (const float*)d_in[10];
    const float* hW1       = (const float*)d_in[11];
    const float* hb1       = (const float*)d_in[12];
    const float* hW2       = (const float*)d_in[13];
    const float* hb2       = (const float*)d_in[14];
    float* out = (float*)d_out;

    const int N = in_sizes[3];
    const int E = in_sizes[1] / 2;
    const int G = in_sizes[4];
    const int L = in_sizes[10];
    const int ntiles = (N + SCAN_TILE - 1) / SCAN_TILE;

    char* p = (char*)d_ws;
    auto alloc = [&](size_t bytes) { char* r = p; p += (bytes + 255) & ~(size_t)255; return r; };
    int*   rowptr = (int*)  alloc((size_t)(N + 1) * 4);
    int*   fillc  = (int*)  alloc((size_t)N * 4);
    int*   srcs   = (int*)  alloc((size_t)E * 4);
    int*   tsum   = (int*)  alloc((size_t)ntiles * 4);
    int*   starts = (int*)  alloc((size_t)(G + 1) * 4);
    float* bufA   = (float*)alloc((size_t)N * NDIM * 4);
    float* bufB   = (float*)alloc((size_t)N * NDIM * 4);
    size_t base_used = (size_t)(p - (char*)d_ws);
    float* gea    = (float*)alloc((size_t)E * EDIM * 4);
    bool use_gea = (base_used + (size_t)E * EDIM * 4) <= ws_size;
    int* eids = use_gea ? nullptr : (int*)((char*)d_ws + base_used);

    // --- CSR build ---
    hipMemsetAsync(fillc, 0, (size_t)N * 4, stream);
    hist_kernel<<<(E + 255) / 256, 256, 0, stream>>>(edge_index, fillc, E);
    scan_tile_kernel<<<ntiles, SCAN_BS, 0, stream>>>(fillc, rowptr, tsum, N);
    scan_sums_kernel<<<1, 64, 0, stream>>>(tsum, ntiles);
    scan_add_kernel<<<(N + 255) / 256, 256, 0, stream>>>(rowptr, tsum, fillc, N, E);
    if (use_gea) {
        fill2_kernel<<<(E + 255) / 256, 256, 0, stream>>>(edge_index, fillc, srcs,
                                                          (float4*)gea, (const float4*)edge_attr, E);
    } else {
        fill_kernel<<<(E + 255) / 256, 256, 0, stream>>>(edge_index, fillc, srcs, eids, E);
    }
    starts_kernel<<<(G + 256) / 256, 256, 0, stream>>>(batch, starts, N, G);

    // --- 4 GINEConv layers ---
    const float* cur = x_in;
    float* work = bufA;
    for (int l = 0; l < L; ++l) {
        if (use_gea) {
            aggr_kernel<<<2048, 256, 0, stream>>>(cur, work, rowptr, srcs, gea, lin_e, eps, l, N);
            mlp_kernel<<<2048, 256, 0, stream>>>(work, W1, b1, W2, b2, l, N);
            cur = work;
            work = (work == bufA) ? bufB : bufA;
        } else {
            layer_kernel<<<1024, 256, 0, stream>>>(cur, work, rowptr, srcs, eids,
                                                   edge_attr, lin_e, W1, b1, W2, b2, eps, l, N);
            cur = work;
            work = (work == bufA) ? bufB : bufA;
        }
    }

    // --- pool + head (atomic-free) ---
    poolhead_kernel<<<128, 256, 0, stream>>>(cur, starts, t_cond, hW1, hb1, hW2, hb2, out, G);
}

// Round 4
// 951.527 us; speedup vs baseline: 1.6535x; 1.6535x over previous
//
#include <hip/hip_runtime.h>

#define NDIM 64
#define EDIM 16
#define SCAN_BS 256
#define SCAN_TILE 2048   // SCAN_BS * 8

typedef __attribute__((ext_vector_type(8))) short short8;   // 8 x bf16 (4 VGPR)
typedef __attribute__((ext_vector_type(4))) float f32x4;    // MFMA acc

// ---------------- bf16 hi/lo helpers ----------------
__device__ inline unsigned short f2bf_rne(float f) {
    unsigned int u = __float_as_uint(f);
    unsigned int r = u + 0x7FFFu + ((u >> 16) & 1u);
    return (unsigned short)(r >> 16);
}
__device__ inline float bf2f(unsigned short h) {
    return __uint_as_float(((unsigned int)h) << 16);
}
__device__ inline void cvt8(const float4 v0, const float4 v1, short8& hi, short8& lo) {
    float v[8] = {v0.x, v0.y, v0.z, v0.w, v1.x, v1.y, v1.z, v1.w};
#pragma unroll
    for (int j = 0; j < 8; ++j) {
        unsigned short h = f2bf_rne(v[j]);
        hi[j] = (short)h;
        lo[j] = (short)f2bf_rne(v[j] - bf2f(h));
    }
}

// ---------------- CSR build ----------------

__global__ __launch_bounds__(256) void hist_kernel(const int* __restrict__ edge_index,
                                                   int* __restrict__ deg, int E) {
    int e = blockIdx.x * blockDim.x + threadIdx.x;
    if (e < E) atomicAdd(&deg[edge_index[E + e]], 1);   // dst row
}

__global__ __launch_bounds__(SCAN_BS) void scan_tile_kernel(const int* __restrict__ deg,
                                                            int* __restrict__ excl,
                                                            int* __restrict__ tsum, int n) {
    __shared__ int sdata[SCAN_BS];
    int base = blockIdx.x * SCAN_TILE + threadIdx.x * 8;
    int v[8]; int s = 0;
#pragma unroll
    for (int j = 0; j < 8; ++j) { int idx = base + j; int val = (idx < n) ? deg[idx] : 0; v[j] = val; s += val; }
    sdata[threadIdx.x] = s;
    __syncthreads();
    for (int off = 1; off < SCAN_BS; off <<= 1) {
        int t = (threadIdx.x >= (unsigned)off) ? sdata[threadIdx.x - off] : 0;
        __syncthreads();
        sdata[threadIdx.x] += t;
        __syncthreads();
    }
    int incl = sdata[threadIdx.x];
    if (threadIdx.x == SCAN_BS - 1) tsum[blockIdx.x] = incl;
    int run = incl - s;
#pragma unroll
    for (int j = 0; j < 8; ++j) { int idx = base + j; if (idx < n) excl[idx] = run; run += v[j]; }
}

__global__ void scan_sums_kernel(int* tsum, int ntiles) {
    if (threadIdx.x == 0 && blockIdx.x == 0) {
        int run = 0;
        for (int i = 0; i < ntiles; ++i) { int t = tsum[i]; tsum[i] = run; run += t; }
    }
}

__global__ __launch_bounds__(256) void scan_add_kernel(int* __restrict__ rowptr,
                                                       const int* __restrict__ tsum,
                                                       int* __restrict__ fillc, int n, int E) {
    int i = blockIdx.x * blockDim.x + threadIdx.x;
    if (i < n) {
        int v = rowptr[i] + tsum[i / SCAN_TILE];
        rowptr[i] = v;
        fillc[i] = v;
    }
    if (i == 0) rowptr[n] = E;
}

__global__ __launch_bounds__(256) void fill2_kernel(const int* __restrict__ edge_index,
                                                    int* __restrict__ fillc,
                                                    int* __restrict__ srcs,
                                                    float4* __restrict__ gea,
                                                    const float4* __restrict__ ea, int E) {
    int e = blockIdx.x * blockDim.x + threadIdx.x;
    if (e < E) {
        int d = edge_index[E + e];
        int pos = atomicAdd(&fillc[d], 1);
        srcs[pos] = edge_index[e];
        float4 r0 = ea[(size_t)e*4+0], r1 = ea[(size_t)e*4+1],
               r2 = ea[(size_t)e*4+2], r3 = ea[(size_t)e*4+3];
        gea[(size_t)pos*4+0] = r0; gea[(size_t)pos*4+1] = r1;
        gea[(size_t)pos*4+2] = r2; gea[(size_t)pos*4+3] = r3;
    }
}

__global__ __launch_bounds__(256) void fill_kernel(const int* __restrict__ edge_index,
                                                   int* __restrict__ fillc,
                                                   int* __restrict__ srcs,
                                                   int* __restrict__ eids, int E) {
    int e = blockIdx.x * blockDim.x + threadIdx.x;
    if (e < E) {
        int d = edge_index[E + e];
        int pos = atomicAdd(&fillc[d], 1);
        srcs[pos] = edge_index[e];
        eids[pos] = e;
    }
}

#define EDGE_FMA16(m, A0, A1, A2, A3)                                   \
    m = fmaf(A0.x, le[ 0], m); m = fmaf(A0.y, le[ 1], m);               \
    m = fmaf(A0.z, le[ 2], m); m = fmaf(A0.w, le[ 3], m);               \
    m = fmaf(A1.x, le[ 4], m); m = fmaf(A1.y, le[ 5], m);               \
    m = fmaf(A1.z, le[ 6], m); m = fmaf(A1.w, le[ 7], m);               \
    m = fmaf(A2.x, le[ 8], m); m = fmaf(A2.y, le[ 9], m);               \
    m = fmaf(A2.z, le[10], m); m = fmaf(A2.w, le[11], m);               \
    m = fmaf(A3.x, le[12], m); m = fmaf(A3.y, le[13], m);               \
    m = fmaf(A3.z, le[14], m); m = fmaf(A3.w, le[15], m);

// ---------------- aggregation kernel (latency phase, zero LDS) ----------------

__global__ __launch_bounds__(256) void aggr_kernel(
    const float* __restrict__ xin, float* __restrict__ hout,
    const int* __restrict__ rowptr, const int* __restrict__ srcs,
    const float* __restrict__ gea,
    const float* __restrict__ lin_e, const float* __restrict__ eps,
    int layer, int n_nodes)
{
    const int lane = threadIdx.x & 63;
    float le[16];
    const float* lep = lin_e + (size_t)layer * EDIM * NDIM;
#pragma unroll
    for (int j = 0; j < EDIM; ++j) le[j] = lep[j * NDIM + lane];
    const float eps1 = 1.0f + eps[layer];

    int gw = (blockIdx.x * blockDim.x + threadIdx.x) >> 6;
    int nw = (gridDim.x * blockDim.x) >> 6;
    for (int node = gw; node < n_nodes; node += nw) {
        int p0 = rowptr[node], p1 = rowptr[node + 1];
        float aggr = 0.0f;
        for (int base = p0; base < p1; base += 64) {
            int cnt = min(64, p1 - base);
            int s_l = (lane < cnt) ? srcs[base + lane] : 0;
            int p = 0;
            for (; p + 4 <= cnt; p += 4) {
                int s0 = __shfl(s_l, p), s1 = __shfl(s_l, p + 1),
                    s2 = __shfl(s_l, p + 2), s3 = __shfl(s_l, p + 3);
                float xs0 = xin[(size_t)s0 * NDIM + lane];
                float xs1 = xin[(size_t)s1 * NDIM + lane];
                float xs2 = xin[(size_t)s2 * NDIM + lane];
                float xs3 = xin[(size_t)s3 * NDIM + lane];
                const float4* ea = (const float4*)(gea + (size_t)(base + p) * EDIM);
                float4 a0 = ea[ 0], a1 = ea[ 1], a2 = ea[ 2], a3 = ea[ 3];
                float4 e0 = ea[ 4], e1 = ea[ 5], e2 = ea[ 6], e3 = ea[ 7];
                float4 c0 = ea[ 8], c1 = ea[ 9], c2 = ea[10], c3 = ea[11];
                float4 d0 = ea[12], d1 = ea[13], d2 = ea[14], d3 = ea[15];
                float m0 = xs0, m1 = xs1, m2 = xs2, m3 = xs3;
                EDGE_FMA16(m0, a0, a1, a2, a3)
                EDGE_FMA16(m1, e0, e1, e2, e3)
                EDGE_FMA16(m2, c0, c1, c2, c3)
                EDGE_FMA16(m3, d0, d1, d2, d3)
                aggr += fmaxf(m0, 0.0f) + fmaxf(m1, 0.0f) + fmaxf(m2, 0.0f) + fmaxf(m3, 0.0f);
            }
            for (; p < cnt; ++p) {
                int s0 = __shfl(s_l, p);
                float xs0 = xin[(size_t)s0 * NDIM + lane];
                const float4* ea = (const float4*)(gea + (size_t)(base + p) * EDIM);
                float4 a0 = ea[0], a1 = ea[1], a2 = ea[2], a3 = ea[3];
                float m0 = xs0;
                EDGE_FMA16(m0, a0, a1, a2, a3)
                aggr += fmaxf(m0, 0.0f);
            }
        }
        hout[(size_t)node * NDIM + lane] = fmaf(eps1, xin[(size_t)node * NDIM + lane], aggr);
    }
}

// ---------------- MFMA MLP kernel ----------------
// h[N,64] <- relu(relu(h@W1+b1)@W2+b2), in place, one 16-row tile per wave.
// fp32 via bf16 hi/lo split: H@W ~= Hhi@Whi + Hlo@Whi + Hhi@Wlo (rel err ~2^-16).
// Verified layouts: A/B frag [idx=lane&15][k=(lane>>4)*8+j]; C/D col=lane&15,row=(lane>>4)*4+reg.

__global__ __launch_bounds__(256) void mlp_mfma_kernel(
    float* __restrict__ h,
    const float* __restrict__ W1, const float* __restrict__ b1,
    const float* __restrict__ W2, const float* __restrict__ b2,
    int layer, int n_nodes)
{
    // W fragments in LDS, frag-layout index: ((c*4+q)*64 + n)*8 + j  (c=K-chunk, q=lane>>4)
    __shared__ unsigned short sW1hi[4096], sW1lo[4096], sW2hi[4096], sW2lo[4096];
    __shared__ float sY[4][16 * 64];   // per-wave Y scratch, XOR-swizzled 16B granules

    const float* w1 = W1 + (size_t)layer * 4096;
    const float* w2 = W2 + (size_t)layer * 4096;
    for (int idx = threadIdx.x; idx < 4096; idx += 256) {
        int k = idx >> 6, n = idx & 63;
        int c = k >> 5, q = (k >> 3) & 3, j = k & 7;
        int fidx = ((c * 4 + q) * 64 + n) * 8 + j;
        float a = w1[idx];
        unsigned short hi = f2bf_rne(a);
        sW1hi[fidx] = hi;
        sW1lo[fidx] = f2bf_rne(a - bf2f(hi));
        float b = w2[idx];
        hi = f2bf_rne(b);
        sW2hi[fidx] = hi;
        sW2lo[fidx] = f2bf_rne(b - bf2f(hi));
    }
    __syncthreads();

    const int lane = threadIdx.x & 63;
    const int wid = threadIdx.x >> 6;
    const int m = lane & 15, q = lane >> 4;
    float* Y = sY[wid];

    float b1v[4], b2v[4];
#pragma unroll
    for (int nt = 0; nt < 4; ++nt) {
        b1v[nt] = b1[layer * 64 + m + nt * 16];
        b2v[nt] = b2[layer * 64 + m + nt * 16];
    }

    int tiles = (n_nodes + 15) >> 4;
    int gw = blockIdx.x * 4 + wid;
    int nw = gridDim.x * 4;
    for (int t = gw; t < tiles; t += nw) {
        int r0 = t << 4;
        int rA = r0 + m; if (rA > n_nodes - 1) rA = n_nodes - 1;
        const float* hrow = h + (size_t)rA * 64;

        short8 Ahi[2], Alo[2];
#pragma unroll
        for (int c = 0; c < 2; ++c) {
            const float4* hp = (const float4*)(hrow + c * 32 + q * 8);
            float4 v0 = hp[0], v1 = hp[1];
            cvt8(v0, v1, Ahi[c], Alo[c]);
        }

        // ---- GEMM1: Y = relu(H@W1 + b1), into swizzled LDS ----
#pragma unroll
        for (int nt = 0; nt < 4; ++nt) {
            int col = m + nt * 16;
            f32x4 acc = {0.f, 0.f, 0.f, 0.f};
#pragma unroll
            for (int c = 0; c < 2; ++c) {
                short8 bh = *(const short8*)&sW1hi[((c * 4 + q) * 64 + col) * 8];
                short8 bl = *(const short8*)&sW1lo[((c * 4 + q) * 64 + col) * 8];
                acc = __builtin_amdgcn_mfma_f32_16x16x32_bf16(Ahi[c], bh, acc, 0, 0, 0);
                acc = __builtin_amdgcn_mfma_f32_16x16x32_bf16(Alo[c], bh, acc, 0, 0, 0);
                acc = __builtin_amdgcn_mfma_f32_16x16x32_bf16(Ahi[c], bl, acc, 0, 0, 0);
            }
#pragma unroll
            for (int i = 0; i < 4; ++i) {
                int row = q * 4 + i;
                float y = fmaxf(acc[i] + b1v[nt], 0.0f);
                int gran = ((m >> 2) + 4 * nt) ^ row;     // 16B-granule XOR swizzle
                Y[(row << 6) + (gran << 2) + (m & 3)] = y;
            }
        }
        __asm__ volatile("s_waitcnt lgkmcnt(0)" ::: "memory");  // wave-internal LDS exchange

        // ---- Y -> A-fragments (hi/lo) ----
        short8 Yhi[2], Ylo[2];
#pragma unroll
        for (int c = 0; c < 2; ++c) {
            int g0 = c * 8 + q * 2;
            float4 v0 = *(const float4*)&Y[(m << 6) + ((g0 ^ m) << 2)];
            float4 v1 = *(const float4*)&Y[(m << 6) + (((g0 + 1) ^ m) << 2)];
            cvt8(v0, v1, Yhi[c], Ylo[c]);
        }

        // ---- GEMM2: out = relu(Y@W2 + b2) -> global ----
#pragma unroll
        for (int nt = 0; nt < 4; ++nt) {
            int col = m + nt * 16;
            f32x4 acc = {0.f, 0.f, 0.f, 0.f};
#pragma unroll
            for (int c = 0; c < 2; ++c) {
                short8 bh = *(const short8*)&sW2hi[((c * 4 + q) * 64 + col) * 8];
                short8 bl = *(const short8*)&sW2lo[((c * 4 + q) * 64 + col) * 8];
                acc = __builtin_amdgcn_mfma_f32_16x16x32_bf16(Yhi[c], bh, acc, 0, 0, 0);
                acc = __builtin_amdgcn_mfma_f32_16x16x32_bf16(Ylo[c], bh, acc, 0, 0, 0);
                acc = __builtin_amdgcn_mfma_f32_16x16x32_bf16(Yhi[c], bl, acc, 0, 0, 0);
            }
#pragma unroll
            for (int i = 0; i < 4; ++i) {
                int row = r0 + q * 4 + i;
                if (row < n_nodes)
                    h[(size_t)row * 64 + col] = fmaxf(acc[i] + b2v[nt], 0.0f);
            }
        }
    }
}

// fallback fused layer (eids-based) for small ws
__global__ __launch_bounds__(256) void layer_kernel(
    const float* __restrict__ xin, float* __restrict__ xout,
    const int* __restrict__ rowptr, const int* __restrict__ srcs, const int* __restrict__ eids,
    const float* __restrict__ edge_attr,
    const float* __restrict__ lin_e, const float* __restrict__ W1, const float* __restrict__ b1,
    const float* __restrict__ W2, const float* __restrict__ b2, const float* __restrict__ eps,
    int layer, int n_nodes)
{
    __shared__ float s_W1[NDIM * NDIM];
    __shared__ float s_W2[NDIM * NDIM];
    const float* w1 = W1 + (size_t)layer * NDIM * NDIM;
    const float* w2 = W2 + (size_t)layer * NDIM * NDIM;
    for (int i = threadIdx.x; i < NDIM * NDIM; i += 256) { s_W1[i] = w1[i]; s_W2[i] = w2[i]; }
    const int lane = threadIdx.x & 63;
    float le[16];
    const float* lep = lin_e + (size_t)layer * EDIM * NDIM;
#pragma unroll
    for (int j = 0; j < EDIM; ++j) le[j] = lep[j * NDIM + lane];
    const float bb1 = b1[layer * NDIM + lane];
    const float bb2 = b2[layer * NDIM + lane];
    const float eps1 = 1.0f + eps[layer];
    __syncthreads();
    int gw = (blockIdx.x * blockDim.x + threadIdx.x) >> 6;
    int nw = (gridDim.x * blockDim.x) >> 6;
    for (int node = gw; node < n_nodes; node += nw) {
        int p0 = rowptr[node], p1 = rowptr[node + 1];
        float aggr = 0.0f;
        for (int p = p0; p < p1; ++p) {
            int s = srcs[p];
            int e = eids[p];
            float xs = xin[(size_t)s * NDIM + lane];
            const float4* ea = (const float4*)(edge_attr + (size_t)e * EDIM);
            float4 a0 = ea[0], a1 = ea[1], a2 = ea[2], a3 = ea[3];
            float m0 = xs;
            EDGE_FMA16(m0, a0, a1, a2, a3)
            aggr += fmaxf(m0, 0.0f);
        }
        float h = fmaf(eps1, xin[(size_t)node * NDIM + lane], aggr);
        float o1 = bb1;
#pragma unroll 8
        for (int k = 0; k < NDIM; ++k) o1 = fmaf(__shfl(h, k), s_W1[k * NDIM + lane], o1);
        o1 = fmaxf(o1, 0.0f);
        float o2 = bb2;
#pragma unroll 8
        for (int k = 0; k < NDIM; ++k) o2 = fmaf(__shfl(o1, k), s_W2[k * NDIM + lane], o2);
        xout[(size_t)node * NDIM + lane] = fmaxf(o2, 0.0f);
    }
}

// ---------------- pooling + head (atomic-free: batch is sorted) ----------------

__global__ __launch_bounds__(256) void starts_kernel(const int* __restrict__ batch,
                                                     int* __restrict__ starts, int N, int G) {
    int g = blockIdx.x * blockDim.x + threadIdx.x;
    if (g <= G) {
        int lo = 0, hi = N;
        while (lo < hi) { int mid = (lo + hi) >> 1; if (batch[mid] < g) lo = mid + 1; else hi = mid; }
        starts[g] = lo;
    }
}

__global__ __launch_bounds__(256) void poolhead_kernel(const float* __restrict__ x,
                                                       const int* __restrict__ starts,
                                                       const float* __restrict__ t_cond,
                                                       const float* __restrict__ hW1,
                                                       const float* __restrict__ hb1,
                                                       const float* __restrict__ hW2,
                                                       const float* __restrict__ hb2,
                                                       float* __restrict__ out, int G) {
    __shared__ float sW1[(NDIM + 1) * NDIM];
    __shared__ float sb1[NDIM];
    __shared__ float sW2[NDIM];
    for (int i = threadIdx.x; i < (NDIM + 1) * NDIM; i += 256) sW1[i] = hW1[i];
    if (threadIdx.x < NDIM) { sb1[threadIdx.x] = hb1[threadIdx.x]; sW2[threadIdx.x] = hW2[threadIdx.x]; }
    __syncthreads();
    const int lane = threadIdx.x & 63;
    int gw = (blockIdx.x * blockDim.x + threadIdx.x) >> 6;
    int nw = (gridDim.x * blockDim.x) >> 6;
    for (int g = gw; g < G; g += nw) {
        int a = starts[g], b = starts[g + 1];
        float s0 = 0.0f, s1 = 0.0f, s2 = 0.0f, s3 = 0.0f;
        int n = a;
        for (; n + 4 <= b; n += 4) {
            s0 += x[(size_t)n * NDIM + lane];
            s1 += x[(size_t)(n + 1) * NDIM + lane];
            s2 += x[(size_t)(n + 2) * NDIM + lane];
            s3 += x[(size_t)(n + 3) * NDIM + lane];
        }
        for (; n < b; ++n) s0 += x[(size_t)n * NDIM + lane];
        float c = fmaxf((float)(b - a), 1.0f);
        float p = ((s0 + s1) + (s2 + s3)) / c;
        float t = t_cond[g];
        float o1 = fmaf(t, sW1[NDIM * NDIM + lane], sb1[lane]);
#pragma unroll 8
        for (int k = 0; k < NDIM; ++k) o1 = fmaf(__shfl(p, k), sW1[k * NDIM + lane], o1);
        o1 = fmaxf(o1, 0.0f);
        float v = o1 * sW2[lane];
        for (int off = 32; off > 0; off >>= 1) v += __shfl_down(v, off);
        if (lane == 0) out[g] = v + hb2[0];
    }
}

// ---------------- launch ----------------

extern "C" void kernel_launch(void* const* d_in, const int* in_sizes, int n_in,
                              void* d_out, int out_size, void* d_ws, size_t ws_size,
                              hipStream_t stream) {
    const float* x_in      = (const float*)d_in[0];
    const int*   edge_index= (const int*)  d_in[1];
    const float* edge_attr = (const float*)d_in[2];
    const int*   batch     = (const int*)  d_in[3];
    const float* t_cond    = (const float*)d_in[4];
    const float* lin_e     = (const float*)d_in[5];
    const float* W1        = (const float*)d_in[6];
    const float* b1        = (const float*)d_in[7];
    const float* W2        = (const float*)d_in[8];
    const float* b2        = (const float*)d_in[9];
    const float* eps       = (const float*)d_in[10];
    const float* hW1       = (const float*)d_in[11];
    const float* hb1       = (const float*)d_in[12];
    const float* hW2       = (const float*)d_in[13];
    const float* hb2       = (const float*)d_in[14];
    float* out = (float*)d_out;

    const int N = in_sizes[3];
    const int E = in_sizes[1] / 2;
    const int G = in_sizes[4];
    const int L = in_sizes[10];
    const int ntiles = (N + SCAN_TILE - 1) / SCAN_TILE;

    char* p = (char*)d_ws;
    auto alloc = [&](size_t bytes) { char* r = p; p += (bytes + 255) & ~(size_t)255; return r; };
    int*   rowptr = (int*)  alloc((size_t)(N + 1) * 4);
    int*   fillc  = (int*)  alloc((size_t)N * 4);
    int*   srcs   = (int*)  alloc((size_t)E * 4);
    int*   tsum   = (int*)  alloc((size_t)ntiles * 4);
    int*   starts = (int*)  alloc((size_t)(G + 1) * 4);
    float* bufA   = (float*)alloc((size_t)N * NDIM * 4);
    float* bufB   = (float*)alloc((size_t)N * NDIM * 4);
    size_t base_used = (size_t)(p - (char*)d_ws);
    float* gea    = (float*)alloc((size_t)E * EDIM * 4);
    bool use_gea = (base_used + (size_t)E * EDIM * 4) <= ws_size;
    int* eids = use_gea ? nullptr : (int*)((char*)d_ws + base_used);

    // --- CSR build ---
    hipMemsetAsync(fillc, 0, (size_t)N * 4, stream);
    hist_kernel<<<(E + 255) / 256, 256, 0, stream>>>(edge_index, fillc, E);
    scan_tile_kernel<<<ntiles, SCAN_BS, 0, stream>>>(fillc, rowptr, tsum, N);
    scan_sums_kernel<<<1, 64, 0, stream>>>(tsum, ntiles);
    scan_add_kernel<<<(N + 255) / 256, 256, 0, stream>>>(rowptr, tsum, fillc, N, E);
    if (use_gea) {
        fill2_kernel<<<(E + 255) / 256, 256, 0, stream>>>(edge_index, fillc, srcs,
                                                          (float4*)gea, (const float4*)edge_attr, E);
    } else {
        fill_kernel<<<(E + 255) / 256, 256, 0, stream>>>(edge_index, fillc, srcs, eids, E);
    }
    starts_kernel<<<(G + 256) / 256, 256, 0, stream>>>(batch, starts, N, G);

    // --- 4 GINEConv layers ---
    const float* cur = x_in;
    float* work = bufA;
    for (int l = 0; l < L; ++l) {
        if (use_gea) {
            aggr_kernel<<<2048, 256, 0, stream>>>(cur, work, rowptr, srcs, gea, lin_e, eps, l, N);
            mlp_mfma_kernel<<<1024, 256, 0, stream>>>(work, W1, b1, W2, b2, l, N);
            cur = work;
            work = (work == bufA) ? bufB : bufA;
        } else {
            layer_kernel<<<1024, 256, 0, stream>>>(cur, work, rowptr, srcs, eids,
                                                   edge_attr, lin_e, W1, b1, W2, b2, eps, l, N);
            cur = work;
            work = (work == bufA) ? bufB : bufA;
        }
    }

    // --- pool + head (atomic-free) ---
    poolhead_kernel<<<512, 256, 0, stream>>>(cur, starts, t_cond, hW1, hb1, hW2, hb2, out, G);
}

// Round 5
// 677.505 us; speedup vs baseline: 2.3222x; 1.4045x over previous
//
#include <hip/hip_runtime.h>

#define NDIM 64
#define EDIM 16
#define SCAN_BS 256
#define SCAN_TILE 2048   // SCAN_BS * 8

typedef __attribute__((ext_vector_type(8))) short short8;   // 8 x bf16 (4 VGPR)
typedef __attribute__((ext_vector_type(4))) float f32x4;    // MFMA acc
typedef __attribute__((ext_vector_type(4))) float f4;       // raw float4 (no ctor)

// ---------------- scalar (constant AS) load helpers ----------------
// Wave-uniform addresses through address_space(4) let the backend select
// s_load_dword* -> data lands in SGPRs, freeing VGPRs and the VALU.
#define AS4 __attribute__((address_space(4)))
__device__ inline const AS4 int* cs_i(const int* p) {
    return (const AS4 int*)(unsigned long long)p;
}
__device__ inline const AS4 f4* cs_f4(const float* p) {
    return (const AS4 f4*)(unsigned long long)p;
}

// ---------------- bf16 hi/lo helpers ----------------
__device__ inline unsigned short f2bf_rne(float f) {
    unsigned int u = __float_as_uint(f);
    unsigned int r = u + 0x7FFFu + ((u >> 16) & 1u);
    return (unsigned short)(r >> 16);
}
__device__ inline float bf2f(unsigned short h) {
    return __uint_as_float(((unsigned int)h) << 16);
}
__device__ inline void cvt8(const float4 v0, const float4 v1, short8& hi, short8& lo) {
    float v[8] = {v0.x, v0.y, v0.z, v0.w, v1.x, v1.y, v1.z, v1.w};
#pragma unroll
    for (int j = 0; j < 8; ++j) {
        unsigned short h = f2bf_rne(v[j]);
        hi[j] = (short)h;
        lo[j] = (short)f2bf_rne(v[j] - bf2f(h));
    }
}

// ---------------- CSR build ----------------

__global__ __launch_bounds__(256) void hist_kernel(const int* __restrict__ edge_index,
                                                   int* __restrict__ deg, int E) {
    int e = blockIdx.x * blockDim.x + threadIdx.x;
    if (e < E) atomicAdd(&deg[edge_index[E + e]], 1);   // dst row
}

__global__ __launch_bounds__(SCAN_BS) void scan_tile_kernel(const int* __restrict__ deg,
                                                            int* __restrict__ excl,
                                                            int* __restrict__ tsum, int n) {
    __shared__ int sdata[SCAN_BS];
    int base = blockIdx.x * SCAN_TILE + threadIdx.x * 8;
    int v[8]; int s = 0;
#pragma unroll
    for (int j = 0; j < 8; ++j) { int idx = base + j; int val = (idx < n) ? deg[idx] : 0; v[j] = val; s += val; }
    sdata[threadIdx.x] = s;
    __syncthreads();
    for (int off = 1; off < SCAN_BS; off <<= 1) {
        int t = (threadIdx.x >= (unsigned)off) ? sdata[threadIdx.x - off] : 0;
        __syncthreads();
        sdata[threadIdx.x] += t;
        __syncthreads();
    }
    int incl = sdata[threadIdx.x];
    if (threadIdx.x == SCAN_BS - 1) tsum[blockIdx.x] = incl;
    int run = incl - s;
#pragma unroll
    for (int j = 0; j < 8; ++j) { int idx = base + j; if (idx < n) excl[idx] = run; run += v[j]; }
}

__global__ void scan_sums_kernel(int* tsum, int ntiles) {
    if (threadIdx.x == 0 && blockIdx.x == 0) {
        int run = 0;
        for (int i = 0; i < ntiles; ++i) { int t = tsum[i]; tsum[i] = run; run += t; }
    }
}

__global__ __launch_bounds__(256) void scan_add_kernel(int* __restrict__ rowptr,
                                                       const int* __restrict__ tsum,
                                                       int* __restrict__ fillc, int n, int E) {
    int i = blockIdx.x * blockDim.x + threadIdx.x;
    if (i < n) {
        int v = rowptr[i] + tsum[i / SCAN_TILE];
        rowptr[i] = v;
        fillc[i] = v;
    }
    if (i == 0) rowptr[n] = E;
}

__global__ __launch_bounds__(256) void fill2_kernel(const int* __restrict__ edge_index,
                                                    int* __restrict__ fillc,
                                                    int* __restrict__ srcs,
                                                    float4* __restrict__ gea,
                                                    const float4* __restrict__ ea, int E) {
    int e = blockIdx.x * blockDim.x + threadIdx.x;
    if (e < E) {
        int d = edge_index[E + e];
        int pos = atomicAdd(&fillc[d], 1);
        srcs[pos] = edge_index[e];
        float4 r0 = ea[(size_t)e*4+0], r1 = ea[(size_t)e*4+1],
               r2 = ea[(size_t)e*4+2], r3 = ea[(size_t)e*4+3];
        gea[(size_t)pos*4+0] = r0; gea[(size_t)pos*4+1] = r1;
        gea[(size_t)pos*4+2] = r2; gea[(size_t)pos*4+3] = r3;
    }
}

__global__ __launch_bounds__(256) void fill_kernel(const int* __restrict__ edge_index,
                                                   int* __restrict__ fillc,
                                                   int* __restrict__ srcs,
                                                   int* __restrict__ eids, int E) {
    int e = blockIdx.x * blockDim.x + threadIdx.x;
    if (e < E) {
        int d = edge_index[E + e];
        int pos = atomicAdd(&fillc[d], 1);
        srcs[pos] = edge_index[e];
        eids[pos] = e;
    }
}

#define EDGE_FMA16(m, A0, A1, A2, A3)                                   \
    m = fmaf(A0.x, le[ 0], m); m = fmaf(A0.y, le[ 1], m);               \
    m = fmaf(A0.z, le[ 2], m); m = fmaf(A0.w, le[ 3], m);               \
    m = fmaf(A1.x, le[ 4], m); m = fmaf(A1.y, le[ 5], m);               \
    m = fmaf(A1.z, le[ 6], m); m = fmaf(A1.w, le[ 7], m);               \
    m = fmaf(A2.x, le[ 8], m); m = fmaf(A2.y, le[ 9], m);               \
    m = fmaf(A2.z, le[10], m); m = fmaf(A2.w, le[11], m);               \
    m = fmaf(A3.x, le[12], m); m = fmaf(A3.y, le[13], m);               \
    m = fmaf(A3.z, le[14], m); m = fmaf(A3.w, le[15], m);

// ---------------- aggregation kernel (scalar-pipe edge data) ----------------
// One wave per node, lane = channel. rowptr/srcs/gea are wave-uniform ->
// loaded via AS4 (s_load into SGPRs): no shfl chain, ea costs 0 VGPRs,
// v_fma takes SGPR operand. Only x-gathers + hout touch the vector mem pipe.

__global__ __launch_bounds__(256) void aggr_kernel(
    const float* __restrict__ xin, float* __restrict__ hout,
    const int* __restrict__ rowptr, const int* __restrict__ srcs,
    const float* __restrict__ gea,
    const float* __restrict__ lin_e, const float* __restrict__ eps,
    int layer, int n_nodes)
{
    const int lane = threadIdx.x & 63;
    float le[16];
    const float* lep = lin_e + (size_t)layer * EDIM * NDIM;
#pragma unroll
    for (int j = 0; j < EDIM; ++j) le[j] = lep[j * NDIM + lane];
    const float eps1 = 1.0f + eps[layer];

    const AS4 int* rp = cs_i(rowptr);
    const AS4 int* sc = cs_i(srcs);

    int gw = __builtin_amdgcn_readfirstlane((int)((blockIdx.x * blockDim.x + threadIdx.x) >> 6));
    int nw = (gridDim.x * blockDim.x) >> 6;
    for (int node = gw; node < n_nodes; node += nw) {
        int p0 = rp[node], p1 = rp[node + 1];
        float aggr = 0.0f;
        int p = p0;
        for (; p + 4 <= p1; p += 4) {
            int s0 = sc[p], s1 = sc[p + 1], s2 = sc[p + 2], s3 = sc[p + 3];
            float xs0 = xin[(size_t)s0 * NDIM + lane];
            float xs1 = xin[(size_t)s1 * NDIM + lane];
            float xs2 = xin[(size_t)s2 * NDIM + lane];
            float xs3 = xin[(size_t)s3 * NDIM + lane];
            const AS4 f4* ea = cs_f4(gea + (size_t)p * EDIM);
            f4 a0 = ea[ 0], a1 = ea[ 1], a2 = ea[ 2], a3 = ea[ 3];
            f4 e0 = ea[ 4], e1 = ea[ 5], e2 = ea[ 6], e3 = ea[ 7];
            f4 c0 = ea[ 8], c1 = ea[ 9], c2 = ea[10], c3 = ea[11];
            f4 d0 = ea[12], d1 = ea[13], d2 = ea[14], d3 = ea[15];
            float m0 = xs0, m1 = xs1, m2 = xs2, m3 = xs3;
            EDGE_FMA16(m0, a0, a1, a2, a3)
            EDGE_FMA16(m1, e0, e1, e2, e3)
            EDGE_FMA16(m2, c0, c1, c2, c3)
            EDGE_FMA16(m3, d0, d1, d2, d3)
            aggr += fmaxf(m0, 0.0f) + fmaxf(m1, 0.0f) + fmaxf(m2, 0.0f) + fmaxf(m3, 0.0f);
        }
        for (; p < p1; ++p) {          // wave-uniform scalar branch, <=3 iters
            int s0 = sc[p];
            float xs0 = xin[(size_t)s0 * NDIM + lane];
            const AS4 f4* ea = cs_f4(gea + (size_t)p * EDIM);
            f4 a0 = ea[0], a1 = ea[1], a2 = ea[2], a3 = ea[3];
            float m0 = xs0;
            EDGE_FMA16(m0, a0, a1, a2, a3)
            aggr += fmaxf(m0, 0.0f);
        }
        hout[(size_t)node * NDIM + lane] = fmaf(eps1, xin[(size_t)node * NDIM + lane], aggr);
    }
}

// ---------------- MFMA MLP kernel ----------------
// h[N,64] <- relu(relu(h@W1+b1)@W2+b2), in place, one 16-row tile per wave.
// fp32 via bf16 hi/lo split: H@W ~= Hhi@Whi + Hlo@Whi + Hhi@Wlo.

__global__ __launch_bounds__(256) void mlp_mfma_kernel(
    float* __restrict__ h,
    const float* __restrict__ W1, const float* __restrict__ b1,
    const float* __restrict__ W2, const float* __restrict__ b2,
    int layer, int n_nodes)
{
    __shared__ unsigned short sW1hi[4096], sW1lo[4096], sW2hi[4096], sW2lo[4096];
    __shared__ float sY[4][16 * 64];   // per-wave Y scratch, XOR-swizzled 16B granules

    const float* w1 = W1 + (size_t)layer * 4096;
    const float* w2 = W2 + (size_t)layer * 4096;
    for (int idx = threadIdx.x; idx < 4096; idx += 256) {
        int k = idx >> 6, n = idx & 63;
        int c = k >> 5, q = (k >> 3) & 3, j = k & 7;
        int fidx = ((c * 4 + q) * 64 + n) * 8 + j;
        float a = w1[idx];
        unsigned short hi = f2bf_rne(a);
        sW1hi[fidx] = hi;
        sW1lo[fidx] = f2bf_rne(a - bf2f(hi));
        float b = w2[idx];
        hi = f2bf_rne(b);
        sW2hi[fidx] = hi;
        sW2lo[fidx] = f2bf_rne(b - bf2f(hi));
    }
    __syncthreads();

    const int lane = threadIdx.x & 63;
    const int wid = threadIdx.x >> 6;
    const int m = lane & 15, q = lane >> 4;
    float* Y = sY[wid];

    float b1v[4], b2v[4];
#pragma unroll
    for (int nt = 0; nt < 4; ++nt) {
        b1v[nt] = b1[layer * 64 + m + nt * 16];
        b2v[nt] = b2[layer * 64 + m + nt * 16];
    }

    int tiles = (n_nodes + 15) >> 4;
    int gw = blockIdx.x * 4 + wid;
    int nw = gridDim.x * 4;
    for (int t = gw; t < tiles; t += nw) {
        int r0 = t << 4;
        int rA = r0 + m; if (rA > n_nodes - 1) rA = n_nodes - 1;
        const float* hrow = h + (size_t)rA * 64;

        short8 Ahi[2], Alo[2];
#pragma unroll
        for (int c = 0; c < 2; ++c) {
            const float4* hp = (const float4*)(hrow + c * 32 + q * 8);
            float4 v0 = hp[0], v1 = hp[1];
            cvt8(v0, v1, Ahi[c], Alo[c]);
        }

        // ---- GEMM1: Y = relu(H@W1 + b1), into swizzled LDS ----
#pragma unroll
        for (int nt = 0; nt < 4; ++nt) {
            int col = m + nt * 16;
            f32x4 acc = {0.f, 0.f, 0.f, 0.f};
#pragma unroll
            for (int c = 0; c < 2; ++c) {
                short8 bh = *(const short8*)&sW1hi[((c * 4 + q) * 64 + col) * 8];
                short8 bl = *(const short8*)&sW1lo[((c * 4 + q) * 64 + col) * 8];
                acc = __builtin_amdgcn_mfma_f32_16x16x32_bf16(Ahi[c], bh, acc, 0, 0, 0);
                acc = __builtin_amdgcn_mfma_f32_16x16x32_bf16(Alo[c], bh, acc, 0, 0, 0);
                acc = __builtin_amdgcn_mfma_f32_16x16x32_bf16(Ahi[c], bl, acc, 0, 0, 0);
            }
#pragma unroll
            for (int i = 0; i < 4; ++i) {
                int row = q * 4 + i;
                float y = fmaxf(acc[i] + b1v[nt], 0.0f);
                int gran = ((m >> 2) + 4 * nt) ^ row;     // 16B-granule XOR swizzle
                Y[(row << 6) + (gran << 2) + (m & 3)] = y;
            }
        }
        __asm__ volatile("s_waitcnt lgkmcnt(0)" ::: "memory");  // wave-internal LDS exchange

        // ---- Y -> A-fragments (hi/lo) ----
        short8 Yhi[2], Ylo[2];
#pragma unroll
        for (int c = 0; c < 2; ++c) {
            int g0 = c * 8 + q * 2;
            float4 v0 = *(const float4*)&Y[(m << 6) + ((g0 ^ m) << 2)];
            float4 v1 = *(const float4*)&Y[(m << 6) + (((g0 + 1) ^ m) << 2)];
            cvt8(v0, v1, Yhi[c], Ylo[c]);
        }

        // ---- GEMM2: out = relu(Y@W2 + b2) -> global ----
#pragma unroll
        for (int nt = 0; nt < 4; ++nt) {
            int col = m + nt * 16;
            f32x4 acc = {0.f, 0.f, 0.f, 0.f};
#pragma unroll
            for (int c = 0; c < 2; ++c) {
                short8 bh = *(const short8*)&sW2hi[((c * 4 + q) * 64 + col) * 8];
                short8 bl = *(const short8*)&sW2lo[((c * 4 + q) * 64 + col) * 8];
                acc = __builtin_amdgcn_mfma_f32_16x16x32_bf16(Yhi[c], bh, acc, 0, 0, 0);
                acc = __builtin_amdgcn_mfma_f32_16x16x32_bf16(Ylo[c], bh, acc, 0, 0, 0);
                acc = __builtin_amdgcn_mfma_f32_16x16x32_bf16(Yhi[c], bl, acc, 0, 0, 0);
            }
#pragma unroll
            for (int i = 0; i < 4; ++i) {
                int row = r0 + q * 4 + i;
                if (row < n_nodes)
                    h[(size_t)row * 64 + col] = fmaxf(acc[i] + b2v[nt], 0.0f);
            }
        }
    }
}

// fallback fused layer (eids-based) for small ws
__global__ __launch_bounds__(256) void layer_kernel(
    const float* __restrict__ xin, float* __restrict__ xout,
    const int* __restrict__ rowptr, const int* __restrict__ srcs, const int* __restrict__ eids,
    const float* __restrict__ edge_attr,
    const float* __restrict__ lin_e, const float* __restrict__ W1, const float* __restrict__ b1,
    const float* __restrict__ W2, const float* __restrict__ b2, const float* __restrict__ eps,
    int layer, int n_nodes)
{
    __shared__ float s_W1[NDIM * NDIM];
    __shared__ float s_W2[NDIM * NDIM];
    const float* w1 = W1 + (size_t)layer * NDIM * NDIM;
    const float* w2 = W2 + (size_t)layer * NDIM * NDIM;
    for (int i = threadIdx.x; i < NDIM * NDIM; i += 256) { s_W1[i] = w1[i]; s_W2[i] = w2[i]; }
    const int lane = threadIdx.x & 63;
    float le[16];
    const float* lep = lin_e + (size_t)layer * EDIM * NDIM;
#pragma unroll
    for (int j = 0; j < EDIM; ++j) le[j] = lep[j * NDIM + lane];
    const float bb1 = b1[layer * NDIM + lane];
    const float bb2 = b2[layer * NDIM + lane];
    const float eps1 = 1.0f + eps[layer];
    __syncthreads();
    int gw = (blockIdx.x * blockDim.x + threadIdx.x) >> 6;
    int nw = (gridDim.x * blockDim.x) >> 6;
    for (int node = gw; node < n_nodes; node += nw) {
        int p0 = rowptr[node], p1 = rowptr[node + 1];
        float aggr = 0.0f;
        for (int p = p0; p < p1; ++p) {
            int s = srcs[p];
            int e = eids[p];
            float xs = xin[(size_t)s * NDIM + lane];
            const float4* ea = (const float4*)(edge_attr + (size_t)e * EDIM);
            float4 a0 = ea[0], a1 = ea[1], a2 = ea[2], a3 = ea[3];
            float m0 = xs;
            EDGE_FMA16(m0, a0, a1, a2, a3)
            aggr += fmaxf(m0, 0.0f);
        }
        float h = fmaf(eps1, xin[(size_t)node * NDIM + lane], aggr);
        float o1 = bb1;
#pragma unroll 8
        for (int k = 0; k < NDIM; ++k) o1 = fmaf(__shfl(h, k), s_W1[k * NDIM + lane], o1);
        o1 = fmaxf(o1, 0.0f);
        float o2 = bb2;
#pragma unroll 8
        for (int k = 0; k < NDIM; ++k) o2 = fmaf(__shfl(o1, k), s_W2[k * NDIM + lane], o2);
        xout[(size_t)node * NDIM + lane] = fmaxf(o2, 0.0f);
    }
}

// ---------------- pooling + head (atomic-free: batch is sorted) ----------------

__global__ __launch_bounds__(256) void starts_kernel(const int* __restrict__ batch,
                                                     int* __restrict__ starts, int N, int G) {
    int g = blockIdx.x * blockDim.x + threadIdx.x;
    if (g <= G) {
        int lo = 0, hi = N;
        while (lo < hi) { int mid = (lo + hi) >> 1; if (batch[mid] < g) lo = mid + 1; else hi = mid; }
        starts[g] = lo;
    }
}

__global__ __launch_bounds__(256) void poolhead_kernel(const float* __restrict__ x,
                                                       const int* __restrict__ starts,
                                                       const float* __restrict__ t_cond,
                                                       const float* __restrict__ hW1,
                                                       const float* __restrict__ hb1,
                                                       const float* __restrict__ hW2,
                                                       const float* __restrict__ hb2,
                                                       float* __restrict__ out, int G) {
    __shared__ float sW1[(NDIM + 1) * NDIM];
    __shared__ float sb1[NDIM];
    __shared__ float sW2[NDIM];
    for (int i = threadIdx.x; i < (NDIM + 1) * NDIM; i += 256) sW1[i] = hW1[i];
    if (threadIdx.x < NDIM) { sb1[threadIdx.x] = hb1[threadIdx.x]; sW2[threadIdx.x] = hW2[threadIdx.x]; }
    __syncthreads();
    const int lane = threadIdx.x & 63;
    int gw = (blockIdx.x * blockDim.x + threadIdx.x) >> 6;
    int nw = (gridDim.x * blockDim.x) >> 6;
    for (int g = gw; g < G; g += nw) {
        int a = starts[g], b = starts[g + 1];
        float s0 = 0.0f, s1 = 0.0f, s2 = 0.0f, s3 = 0.0f;
        int n = a;
        for (; n + 4 <= b; n += 4) {
            s0 += x[(size_t)n * NDIM + lane];
            s1 += x[(size_t)(n + 1) * NDIM + lane];
            s2 += x[(size_t)(n + 2) * NDIM + lane];
            s3 += x[(size_t)(n + 3) * NDIM + lane];
        }
        for (; n < b; ++n) s0 += x[(size_t)n * NDIM + lane];
        float c = fmaxf((float)(b - a), 1.0f);
        float p = ((s0 + s1) + (s2 + s3)) / c;
        float t = t_cond[g];
        float o1 = fmaf(t, sW1[NDIM * NDIM + lane], sb1[lane]);
#pragma unroll 8
        for (int k = 0; k < NDIM; ++k) o1 = fmaf(__shfl(p, k), sW1[k * NDIM + lane], o1);
        o1 = fmaxf(o1, 0.0f);
        float v = o1 * sW2[lane];
        for (int off = 32; off > 0; off >>= 1) v += __shfl_down(v, off);
        if (lane == 0) out[g] = v + hb2[0];
    }
}

// ---------------- launch ----------------

extern "C" void kernel_launch(void* const* d_in, const int* in_sizes, int n_in,
                              void* d_out, int out_size, void* d_ws, size_t ws_size,
                              hipStream_t stream) {
    const float* x_in      = (const float*)d_in[0];
    const int*   edge_index= (const int*)  d_in[1];
    const float* edge_attr = (const float*)d_in[2];
    const int*   batch     = (const int*)  d_in[3];
    const float* t_cond    = (const float*)d_in[4];
    const float* lin_e     = (const float*)d_in[5];
    const float* W1        = (const float*)d_in[6];
    const float* b1        = (const float*)d_in[7];
    const float* W2        = (const float*)d_in[8];
    const float* b2        = (const float*)d_in[9];
    const float* eps       = (const float*)d_in[10];
    const float* hW1       = (const float*)d_in[11];
    const float* hb1       = (const float*)d_in[12];
    const float* hW2       = (const float*)d_in[13];
    const float* hb2       = (const float*)d_in[14];
    float* out = (float*)d_out;

    const int N = in_sizes[3];
    const int E = in_sizes[1] / 2;
    const int G = in_sizes[4];
    const int L = in_sizes[10];
    const int ntiles = (N + SCAN_TILE - 1) / SCAN_TILE;

    char* p = (char*)d_ws;
    auto alloc = [&](size_t bytes) { char* r = p; p += (bytes + 255) & ~(size_t)255; return r; };
    int*   rowptr = (int*)  alloc((size_t)(N + 1) * 4);
    int*   fillc  = (int*)  alloc((size_t)N * 4);
    int*   srcs   = (int*)  alloc((size_t)E * 4);
    int*   tsum   = (int*)  alloc((size_t)ntiles * 4);
    int*   starts = (int*)  alloc((size_t)(G + 1) * 4);
    float* bufA   = (float*)alloc((size_t)N * NDIM * 4);
    float* bufB   = (float*)alloc((size_t)N * NDIM * 4);
    size_t base_used = (size_t)(p - (char*)d_ws);
    float* gea    = (float*)alloc((size_t)E * EDIM * 4);
    bool use_gea = (base_used + (size_t)E * EDIM * 4) <= ws_size;
    int* eids = use_gea ? nullptr : (int*)((char*)d_ws + base_used);

    // --- CSR build ---
    hipMemsetAsync(fillc, 0, (size_t)N * 4, stream);
    hist_kernel<<<(E + 255) / 256, 256, 0, stream>>>(edge_index, fillc, E);
    scan_tile_kernel<<<ntiles, SCAN_BS, 0, stream>>>(fillc, rowptr, tsum, N);
    scan_sums_kernel<<<1, 64, 0, stream>>>(tsum, ntiles);
    scan_add_kernel<<<(N + 255) / 256, 256, 0, stream>>>(rowptr, tsum, fillc, N, E);
    if (use_gea) {
        fill2_kernel<<<(E + 255) / 256, 256, 0, stream>>>(edge_index, fillc, srcs,
                                                          (float4*)gea, (const float4*)edge_attr, E);
    } else {
        fill_kernel<<<(E + 255) / 256, 256, 0, stream>>>(edge_index, fillc, srcs, eids, E);
    }
    starts_kernel<<<(G + 256) / 256, 256, 0, stream>>>(batch, starts, N, G);

    // --- 4 GINEConv layers ---
    const float* cur = x_in;
    float* work = bufA;
    for (int l = 0; l < L; ++l) {
        if (use_gea) {
            aggr_kernel<<<2048, 256, 0, stream>>>(cur, work, rowptr, srcs, gea, lin_e, eps, l, N);
            mlp_mfma_kernel<<<1024, 256, 0, stream>>>(work, W1, b1, W2, b2, l, N);
            cur = work;
            work = (work == bufA) ? bufB : bufA;
        } else {
            layer_kernel<<<1024, 256, 0, stream>>>(cur, work, rowptr, srcs, eids,
                                                   edge_attr, lin_e, W1, b1, W2, b2, eps, l, N);
            cur = work;
            work = (work == bufA) ? bufB : bufA;
        }
    }

    // --- pool + head (atomic-free) ---
    poolhead_kernel<<<512, 256, 0, stream>>>(cur, starts, t_cond, hW1, hb1, hW2, hb2, out, G);
}